// Round 6
// baseline (182.358 us; speedup 1.0000x reference)
//
#include <hip/hip_runtime.h>

typedef float v4f __attribute__((ext_vector_type(4)));
typedef short v8s __attribute__((ext_vector_type(8)));

#define BM 64

__device__ __forceinline__ unsigned short f2bf(float f) {
    union { float f; unsigned u; } v; v.f = f;
    unsigned u = v.u;
    u += 0x7FFFu + ((u >> 16) & 1u);   // round-to-nearest-even
    return (unsigned short)(u >> 16);
}

// pack two f32 -> two bf16 (RNE) in one instruction
__device__ __forceinline__ unsigned cvt_pk_bf16(float lo, float hi) {
    unsigned r;
    asm("v_cvt_pk_bf16_f32 %0, %1, %2" : "=v"(r) : "v"(lo), "v"(hi));
    return r;
}

__device__ __forceinline__ float fast_exp2(float x) {
#if __has_builtin(__builtin_amdgcn_exp2f)
    return __builtin_amdgcn_exp2f(x);
#else
    return exp2f(x);
#endif
}
__device__ __forceinline__ float fast_rcp(float x) {
#if __has_builtin(__builtin_amdgcn_rcpf)
    return __builtin_amdgcn_rcpf(x);
#else
    return 1.0f / x;
#endif
}
__device__ __forceinline__ float fast_tanh(float y) {
    float t = fast_exp2(y * 2.885390081777927f);
    return (t - 1.0f) * fast_rcp(t + 1.0f);
}
__device__ __forceinline__ float fast_sigmoid(float z) {
    float t = fast_exp2(-1.4426950408889634f * z);
    return fast_rcp(1.0f + t);
}

// ---------------------------------------------------------------------------
// Pack 5 weight matrices (fp32 row-major [N][K]) into bf16 MFMA-B-fragment
// order (canonical 16x32 tile: lane = ((k>>3)&3)*16 + (n&15), j = k&7).
// ws layout: Wb(98304) | W1(65536) | W2 | Wa | Wt   (bf16 elems)
// ---------------------------------------------------------------------------
__global__ void prep_pack(const float* __restrict__ Wb, const float* __restrict__ W1,
                          const float* __restrict__ W2, const float* __restrict__ Wa,
                          const float* __restrict__ Wt, unsigned short* __restrict__ ws)
{
    int e = blockIdx.x * 256 + threadIdx.x;
    if (e >= 360448) return;
    const float* src; int K; int base;
    if (e < 98304)       { src = Wb; K = 384; base = 0; }
    else if (e < 163840) { src = W1; K = 256; base = 98304; }
    else if (e < 229376) { src = W2; K = 256; base = 163840; }
    else if (e < 294912) { src = Wa; K = 256; base = 229376; }
    else                 { src = Wt; K = 256; base = 294912; }
    int le   = e - base;
    int j    = le & 7;
    int lane = (le >> 3) & 63;
    int tile = le >> 9;
    int kt   = K >> 5;
    int ks   = tile % kt;
    int nt   = tile / kt;
    int n = nt * 16 + (lane & 15);
    int k = ks * 32 + (lane >> 4) * 8 + j;
    ws[e] = f2bf(src[n * K + k]);
}

// ---------------------------------------------------------------------------
// Fused CfC cell, BM=64 rows/block, 4 waves each owning 64 output cols.
// LDS 32KB. __launch_bounds__(256,3): 170-reg budget so the fully-unrolled
// k-loops (16-32 independent B loads in flight, compiler-scheduled vmcnt)
// fit WITHOUT scratch spill. Structure otherwise identical to the verified
// Round-2 kernel (best so far).
// phase 1: X = lecun_tanh([in|hx] @ Wb^T + bb)   (K=384)
// phase 2: 4 simultaneous GEMMs over X (K=256) + fused epilogue
// ---------------------------------------------------------------------------
__global__ __launch_bounds__(256, 3) void cfc_fused(
    const float* __restrict__ xin, const float* __restrict__ hx,
    const float* __restrict__ ts,
    const float* __restrict__ bb, const float* __restrict__ b1,
    const float* __restrict__ b2, const float* __restrict__ ba,
    const float* __restrict__ bt,
    const unsigned short* __restrict__ wpk,
    float* __restrict__ out)
{
    __shared__ unsigned short lds[16384];   // 32 KB
    const int tid  = threadIdx.x;
    const int lane = tid & 63;
    const int w    = tid >> 6;        // wave id = output-col group (64 cols)
    const int row0 = blockIdx.x * BM;

    // ---------------- phase 1: backbone GEMM, acc[nt][mt] -------------------
    v4f acc[4][4];
    #pragma unroll
    for (int nt = 0; nt < 4; ++nt) {
        float bv = bb[w * 64 + nt * 16 + (lane & 15)];
        v4f bvv = {bv, bv, bv, bv};
        #pragma unroll
        for (int mt = 0; mt < 4; ++mt) acc[nt][mt] = bvv;
    }

    #pragma unroll 1
    for (int c = 0; c < 3; ++c) {   // K chunks: in[0:128], hx[0:128], hx[128:256]
        const float* src = (c == 0) ? (xin + (size_t)row0 * 128)
                                    : (hx + (size_t)row0 * 256 + (c == 2 ? 128 : 0));
        const int srcld = (c == 0) ? 128 : 256;
        __syncthreads();            // previous chunk fully consumed
        #pragma unroll
        for (int it = 0; it < 8; ++it) {
            int i  = tid + it * 256;        // 0..2047 float4s of a 64x128 tile
            int r  = i >> 5;
            int c4 = i & 31;
            v4f v = *(reinterpret_cast<const v4f*>(src + (size_t)r * srcld) + c4);
            uint2 pk;
            pk.x = cvt_pk_bf16(v[0], v[1]);
            pk.y = cvt_pk_bf16(v[2], v[3]);
            int idx = (((r >> 4) * 4 + (c4 >> 3)) * 64 + ((c4 >> 1) & 3) * 16 + (r & 15)) * 8
                      + (c4 & 1) * 4;
            *reinterpret_cast<uint2*>(&lds[idx]) = pk;
        }
        __syncthreads();
        #pragma unroll
        for (int ksl = 0; ksl < 4; ++ksl) {
            v8s a[4];
            #pragma unroll
            for (int mt = 0; mt < 4; ++mt)
                a[mt] = *reinterpret_cast<const v8s*>(&lds[((mt*4 + ksl)*64 + lane)*8]);
            const int gks = c * 4 + ksl;
            #pragma unroll
            for (int nt = 0; nt < 4; ++nt) {
                v8s b = *reinterpret_cast<const v8s*>(
                            wpk + ((size_t)((w*4 + nt)*12 + gks)*64 + lane)*8);
                #pragma unroll
                for (int mt = 0; mt < 4; ++mt)
                    acc[nt][mt] = __builtin_amdgcn_mfma_f32_16x16x32_bf16(a[mt], b, acc[nt][mt], 0, 0, 0);
            }
        }
    }
    __syncthreads();

    // ------------- activation + write X to LDS in packed A-frag layout ------
    // D elem: row = mt*16+(lane>>4)*4+r, k2 = w*64+nt*16+(lane&15)
    #pragma unroll
    for (int nt = 0; nt < 4; ++nt)
        #pragma unroll
        for (int mt = 0; mt < 4; ++mt)
            #pragma unroll
            for (int r = 0; r < 4; ++r) {
                float xv = 1.7159f * fast_tanh(0.666f * acc[nt][mt][r]);
                int idx = ((mt*8 + w*2 + (nt >> 1)) * 64
                           + ((nt & 1)*2 + ((lane >> 3) & 1)) * 16 + (lane >> 4)*4 + r) * 8
                          + (lane & 7);
                lds[idx] = f2bf(xv);
            }
    __syncthreads();

    // ---------------- phase 2: 4 GEMMs over X + fused epilogue --------------
    const unsigned short* wmp = wpk + 98304;   // W1,W2,Wa,Wt each 65536 elems
    #pragma unroll 1
    for (int g = 0; g < 4; ++g) {              // n-tiles (16 cols each)
        const int n = w * 64 + g * 16 + (lane & 15);
        v4f a2[4][4];                          // [mat][mt]
        {
            float v1 = b1[n], v2 = b2[n], va = ba[n], vt = bt[n];
            v4f q1 = {v1,v1,v1,v1}, q2 = {v2,v2,v2,v2}, qa = {va,va,va,va}, qt = {vt,vt,vt,vt};
            #pragma unroll
            for (int mt = 0; mt < 4; ++mt) {
                a2[0][mt] = q1; a2[1][mt] = q2; a2[2][mt] = qa; a2[3][mt] = qt;
            }
        }
        #pragma unroll
        for (int ks = 0; ks < 8; ++ks) {
            v8s a[4];
            #pragma unroll
            for (int mt = 0; mt < 4; ++mt)
                a[mt] = *reinterpret_cast<const v8s*>(&lds[((mt*8 + ks)*64 + lane)*8]);
            const int tile = ((w*4 + g)*8 + ks)*64;
            #pragma unroll
            for (int mat = 0; mat < 4; ++mat) {
                v8s b = *reinterpret_cast<const v8s*>(wmp + (size_t)mat*65536 + ((size_t)tile + lane)*8);
                #pragma unroll
                for (int mt = 0; mt < 4; ++mt)
                    a2[mat][mt] = __builtin_amdgcn_mfma_f32_16x16x32_bf16(a[mt], b, a2[mat][mt], 0, 0, 0);
            }
        }
        // fused epilogue: ff1, ff2, t_interp, blend, store
        #pragma unroll
        for (int mt = 0; mt < 4; ++mt) {
            int rowb = row0 + mt*16 + ((lane >> 4) << 2);
            #pragma unroll
            for (int r = 0; r < 4; ++r) {
                float tsv = ts[rowb + r];
                float ff1 = fast_tanh(a2[0][mt][r]);
                float ff2 = fast_tanh(a2[1][mt][r]);
                float ti  = fast_sigmoid(a2[2][mt][r] * tsv + a2[3][mt][r]);
                out[(size_t)(rowb + r) * 256 + n] = ff1 + ti * (ff2 - ff1);
            }
        }
    }
}

extern "C" void kernel_launch(void* const* d_in, const int* in_sizes, int n_in,
                              void* d_out, int out_size, void* d_ws, size_t ws_size,
                              hipStream_t stream)
{
    const float* xin = (const float*)d_in[0];
    const float* hx  = (const float*)d_in[1];
    const float* ts  = (const float*)d_in[2];
    const float* Wb  = (const float*)d_in[3];
    const float* bb  = (const float*)d_in[4];
    const float* W1  = (const float*)d_in[5];
    const float* b1  = (const float*)d_in[6];
    const float* W2  = (const float*)d_in[7];
    const float* b2  = (const float*)d_in[8];
    const float* Wa  = (const float*)d_in[9];
    const float* ba  = (const float*)d_in[10];
    const float* Wt  = (const float*)d_in[11];
    const float* bt  = (const float*)d_in[12];

    if (ws_size < 360448 * sizeof(unsigned short)) return;
    unsigned short* wpk = (unsigned short*)d_ws;

    prep_pack<<<1408, 256, 0, stream>>>(Wb, W1, W2, Wa, Wt, wpk);
    cfc_fused<<<1024, 256, 0, stream>>>(xin, hx, ts, bb, b1, b2, ba, bt, wpk,
                                        (float*)d_out);
}

// Round 7
// 91.656 us; speedup vs baseline: 1.9896x; 1.9896x over previous
//
#include <hip/hip_runtime.h>

typedef float v4f __attribute__((ext_vector_type(4)));
typedef short v8s __attribute__((ext_vector_type(8)));

#define BM 64

__device__ __forceinline__ unsigned short f2bf(float f) {
    union { float f; unsigned u; } v; v.f = f;
    unsigned u = v.u;
    u += 0x7FFFu + ((u >> 16) & 1u);   // round-to-nearest-even
    return (unsigned short)(u >> 16);
}

// pack two f32 -> two bf16 (RNE) in one instruction
__device__ __forceinline__ unsigned cvt_pk_bf16(float lo, float hi) {
    unsigned r;
    asm("v_cvt_pk_bf16_f32 %0, %1, %2" : "=v"(r) : "v"(lo), "v"(hi));
    return r;
}

// async global->LDS, 16B per lane; LDS dest is WAVE-UNIFORM base + lane*16
__device__ __forceinline__ void gload_lds16(const unsigned short* g, unsigned short* l) {
    __builtin_amdgcn_global_load_lds(
        (const __attribute__((address_space(1))) void*)(const void*)g,
        (__attribute__((address_space(3))) void*)(void*)l,
        16, 0, 0);
}

__device__ __forceinline__ float fast_exp2(float x) {
#if __has_builtin(__builtin_amdgcn_exp2f)
    return __builtin_amdgcn_exp2f(x);
#else
    return exp2f(x);
#endif
}
__device__ __forceinline__ float fast_rcp(float x) {
#if __has_builtin(__builtin_amdgcn_rcpf)
    return __builtin_amdgcn_rcpf(x);
#else
    return 1.0f / x;
#endif
}
__device__ __forceinline__ float fast_tanh(float y) {
    float t = fast_exp2(y * 2.885390081777927f);
    return (t - 1.0f) * fast_rcp(t + 1.0f);
}
__device__ __forceinline__ float fast_sigmoid(float z) {
    float t = fast_exp2(-1.4426950408889634f * z);
    return fast_rcp(1.0f + t);
}

// ---------------------------------------------------------------------------
// Pack 5 weight matrices (fp32 row-major [N][K]) into bf16 MFMA-B-fragment
// order (canonical 16x32 tile: lane = ((k>>3)&3)*16 + (n&15), j = k&7).
// ws layout: Wb(98304) | W1(65536) | W2 | Wa | Wt   (bf16 elems)
// ---------------------------------------------------------------------------
__global__ void prep_pack(const float* __restrict__ Wb, const float* __restrict__ W1,
                          const float* __restrict__ W2, const float* __restrict__ Wa,
                          const float* __restrict__ Wt, unsigned short* __restrict__ ws)
{
    int e = blockIdx.x * 256 + threadIdx.x;
    if (e >= 360448) return;
    const float* src; int K; int base;
    if (e < 98304)       { src = Wb; K = 384; base = 0; }
    else if (e < 163840) { src = W1; K = 256; base = 98304; }
    else if (e < 229376) { src = W2; K = 256; base = 163840; }
    else if (e < 294912) { src = Wa; K = 256; base = 229376; }
    else                 { src = Wt; K = 256; base = 294912; }
    int le   = e - base;
    int j    = le & 7;
    int lane = (le >> 3) & 63;
    int tile = le >> 9;
    int kt   = K >> 5;
    int ks   = tile % kt;
    int nt   = tile / kt;
    int n = nt * 16 + (lane & 15);
    int k = ks * 32 + (lane >> 4) * 8 + j;
    ws[e] = f2bf(src[n * K + k]);
}

// ---------------------------------------------------------------------------
// Fused CfC cell, BM=64 rows/block, 4 waves each owning 64 output cols.
// Weights stream via global_load_lds into a 2x16KB double buffer (ZERO VGPR
// cost -> no spill possible). Flat 44-step pipeline: steps 0..11 = phase 1
// (c,ksl), steps 12..43 = phase 2 (g,ks). Each step: STAGE(next) -> ds_read
// frags -> 16 MFMA -> barrier (T3 minimal 2-phase recipe).
// LDS 64KB: X/input [0,32KB) + wbuf0 [32,48KB) + wbuf1 [48,64KB).
// 2 blocks/CU; __launch_bounds__(256,2) = 256-reg budget.
// ---------------------------------------------------------------------------
__global__ __launch_bounds__(256, 2) void cfc_fused(
    const float* __restrict__ xin, const float* __restrict__ hx,
    const float* __restrict__ ts,
    const float* __restrict__ bb, const float* __restrict__ b1,
    const float* __restrict__ b2, const float* __restrict__ ba,
    const float* __restrict__ bt,
    const unsigned short* __restrict__ wpk,
    float* __restrict__ out)
{
    __shared__ unsigned short lds[32768];   // 64 KB
    const int tid  = threadIdx.x;
    const int lane = tid & 63;
    const int w    = tid >> 6;        // wave id = output-col group (64 cols)
    const int row0 = blockIdx.x * BM;

    // stage weight tile for flat step s into wbuf pp (4KB per wave, uniform dest)
    auto STAGE = [&](int s, int pp) {
        unsigned short* wb = &lds[16384 + pp * 8192 + w * 2048];
        #pragma unroll
        for (int i = 0; i < 4; ++i) {
            size_t goff;
            if (s < 12) {                       // phase 1: Wb, i = nt
                goff = (size_t)((w * 4 + i) * 12 + s) * 512;
            } else {                            // phase 2: W1/W2/Wa/Wt, i = mat
                int s2 = s - 12, g = s2 >> 3, ks = s2 & 7;
                goff = 98304u + (size_t)i * 65536
                     + (size_t)((w * 4 + g) * 8 + ks) * 512;
            }
            gload_lds16(wpk + goff + (size_t)lane * 8, wb + i * 512);
        }
    };

    int p = 0;
    STAGE(0, 0);                        // prologue: first weight tile in flight

    // ---------------- phase 1: backbone GEMM, acc[nt][mt] -------------------
    v4f acc[4][4];
    #pragma unroll
    for (int nt = 0; nt < 4; ++nt) {
        float bv = bb[w * 64 + nt * 16 + (lane & 15)];
        v4f bvv = {bv, bv, bv, bv};
        #pragma unroll
        for (int mt = 0; mt < 4; ++mt) acc[nt][mt] = bvv;
    }

    #pragma unroll 1
    for (int c = 0; c < 3; ++c) {   // K chunks: in[0:128], hx[0:128], hx[128:256]
        const float* src = (c == 0) ? (xin + (size_t)row0 * 128)
                                    : (hx + (size_t)row0 * 256 + (c == 2 ? 128 : 0));
        const int srcld = (c == 0) ? 128 : 256;
        // issue input loads (overlap the barrier wait)
        v4f stg[8];
        #pragma unroll
        for (int it = 0; it < 8; ++it) {
            int i  = tid + it * 256;
            int r  = i >> 5;
            int c4 = i & 31;
            stg[it] = *(reinterpret_cast<const v4f*>(src + (size_t)r * srcld) + c4);
        }
        __syncthreads();            // previous chunk fully consumed
        #pragma unroll
        for (int it = 0; it < 8; ++it) {
            int i  = tid + it * 256;
            int r  = i >> 5;
            int c4 = i & 31;
            uint2 pk;
            pk.x = cvt_pk_bf16(stg[it][0], stg[it][1]);
            pk.y = cvt_pk_bf16(stg[it][2], stg[it][3]);
            int idx = (((r >> 4) * 4 + (c4 >> 3)) * 64 + ((c4 >> 1) & 3) * 16 + (r & 15)) * 8
                      + (c4 & 1) * 4;
            *reinterpret_cast<uint2*>(&lds[idx]) = pk;
        }
        __syncthreads();            // chunk visible (also drains pending stage)

        #pragma unroll 1
        for (int ksl = 0; ksl < 4; ++ksl) {
            const int s = c * 4 + ksl;
            STAGE(s + 1, p ^ 1);    // next tile's loads fly under this compute
            v8s a[4];
            #pragma unroll
            for (int mt = 0; mt < 4; ++mt)
                a[mt] = *reinterpret_cast<const v8s*>(&lds[((mt*4 + ksl)*64 + lane)*8]);
            const unsigned short* wb = &lds[16384 + p * 8192 + w * 2048];
            v8s bf[4];
            #pragma unroll
            for (int nt = 0; nt < 4; ++nt)
                bf[nt] = *reinterpret_cast<const v8s*>(wb + nt * 512 + lane * 8);
            #pragma unroll
            for (int nt = 0; nt < 4; ++nt)
                #pragma unroll
                for (int mt = 0; mt < 4; ++mt)
                    acc[nt][mt] = __builtin_amdgcn_mfma_f32_16x16x32_bf16(a[mt], bf[nt], acc[nt][mt], 0, 0, 0);
            __syncthreads();        // stage(s+1) complete; wbuf[p] free
            p ^= 1;
        }
    }

    // hoist ts (static indices only; consumed in unrolled epilogue loops)
    float tsh[4][4];
    #pragma unroll
    for (int mt = 0; mt < 4; ++mt)
        #pragma unroll
        for (int r = 0; r < 4; ++r)
            tsh[mt][r] = ts[row0 + mt*16 + ((lane >> 4) << 2) + r];

    // ------------- activation + write X to LDS in packed A-frag layout ------
    // D elem: row = mt*16+(lane>>4)*4+r, k2 = w*64+nt*16+(lane&15)
    #pragma unroll
    for (int nt = 0; nt < 4; ++nt)
        #pragma unroll
        for (int mt = 0; mt < 4; ++mt)
            #pragma unroll
            for (int r = 0; r < 4; ++r) {
                float xv = 1.7159f * fast_tanh(0.666f * acc[nt][mt][r]);
                int idx = ((mt*8 + w*2 + (nt >> 1)) * 64
                           + ((nt & 1)*2 + ((lane >> 3) & 1)) * 16 + (lane >> 4)*4 + r) * 8
                          + (lane & 7);
                lds[idx] = f2bf(xv);
            }
    __syncthreads();

    // ---------------- phase 2: 4 GEMMs over X + fused epilogue --------------
    #pragma unroll 1
    for (int g = 0; g < 4; ++g) {              // n-tiles (16 cols each)
        const int n = w * 64 + g * 16 + (lane & 15);
        v4f a2[4][4];                          // [mat][mt]
        {
            float v1 = b1[n], v2 = b2[n], va = ba[n], vt = bt[n];
            v4f q1 = {v1,v1,v1,v1}, q2 = {v2,v2,v2,v2}, qa = {va,va,va,va}, qt = {vt,vt,vt,vt};
            #pragma unroll
            for (int mt = 0; mt < 4; ++mt) {
                a2[0][mt] = q1; a2[1][mt] = q2; a2[2][mt] = qa; a2[3][mt] = qt;
            }
        }
        #pragma unroll 1
        for (int ks = 0; ks < 8; ++ks) {
            const int s = 12 + g * 8 + ks;
            if (s < 43) STAGE(s + 1, p ^ 1);   // wave-uniform condition
            v8s a[4];
            #pragma unroll
            for (int mt = 0; mt < 4; ++mt)
                a[mt] = *reinterpret_cast<const v8s*>(&lds[((mt*8 + ks)*64 + lane)*8]);
            const unsigned short* wb = &lds[16384 + p * 8192 + w * 2048];
            v8s bf[4];
            #pragma unroll
            for (int mat = 0; mat < 4; ++mat)
                bf[mat] = *reinterpret_cast<const v8s*>(wb + mat * 512 + lane * 8);
            #pragma unroll
            for (int mat = 0; mat < 4; ++mat)
                #pragma unroll
                for (int mt = 0; mt < 4; ++mt)
                    a2[mat][mt] = __builtin_amdgcn_mfma_f32_16x16x32_bf16(a[mt], bf[mat], a2[mat][mt], 0, 0, 0);
            __syncthreads();
            p ^= 1;
        }
        // fused epilogue: ff1, ff2, t_interp, blend, store
        #pragma unroll
        for (int mt = 0; mt < 4; ++mt) {
            int rowb = row0 + mt*16 + ((lane >> 4) << 2);
            #pragma unroll
            for (int r = 0; r < 4; ++r) {
                float ff1 = fast_tanh(a2[0][mt][r]);
                float ff2 = fast_tanh(a2[1][mt][r]);
                float ti  = fast_sigmoid(a2[2][mt][r] * tsh[mt][r] + a2[3][mt][r]);
                out[(size_t)(rowb + r) * 256 + n] = ff1 + ti * (ff2 - ff1);
            }
        }
    }
}

extern "C" void kernel_launch(void* const* d_in, const int* in_sizes, int n_in,
                              void* d_out, int out_size, void* d_ws, size_t ws_size,
                              hipStream_t stream)
{
    const float* xin = (const float*)d_in[0];
    const float* hx  = (const float*)d_in[1];
    const float* ts  = (const float*)d_in[2];
    const float* Wb  = (const float*)d_in[3];
    const float* bb  = (const float*)d_in[4];
    const float* W1  = (const float*)d_in[5];
    const float* b1  = (const float*)d_in[6];
    const float* W2  = (const float*)d_in[7];
    const float* b2  = (const float*)d_in[8];
    const float* Wa  = (const float*)d_in[9];
    const float* ba  = (const float*)d_in[10];
    const float* Wt  = (const float*)d_in[11];
    const float* bt  = (const float*)d_in[12];

    if (ws_size < 360448 * sizeof(unsigned short)) return;
    unsigned short* wpk = (unsigned short*)d_ws;

    prep_pack<<<1408, 256, 0, stream>>>(Wb, W1, W2, Wa, Wt, wpk);
    cfc_fused<<<1024, 256, 0, stream>>>(xin, hx, ts, bb, b1, b2, ba, bt, wpk,
                                        (float*)d_out);
}

// Round 8
// 79.910 us; speedup vs baseline: 2.2820x; 1.1470x over previous
//
#include <hip/hip_runtime.h>

typedef float v4f __attribute__((ext_vector_type(4)));
typedef short v8s __attribute__((ext_vector_type(8)));

#define BM 64

__device__ __forceinline__ unsigned short f2bf(float f) {
    union { float f; unsigned u; } v; v.f = f;
    unsigned u = v.u;
    u += 0x7FFFu + ((u >> 16) & 1u);   // round-to-nearest-even
    return (unsigned short)(u >> 16);
}

// pack two f32 -> two bf16 (RNE) in one instruction
__device__ __forceinline__ unsigned cvt_pk_bf16(float lo, float hi) {
    unsigned r;
    asm("v_cvt_pk_bf16_f32 %0, %1, %2" : "=v"(r) : "v"(lo), "v"(hi));
    return r;
}

// async global->LDS, 16B per lane; LDS dest is WAVE-UNIFORM base + lane*16
__device__ __forceinline__ void gload_lds16(const unsigned short* g, unsigned short* l) {
    __builtin_amdgcn_global_load_lds(
        (const __attribute__((address_space(1))) void*)(const void*)g,
        (__attribute__((address_space(3))) void*)(void*)l,
        16, 0, 0);
}

__device__ __forceinline__ float fast_exp2(float x) {
#if __has_builtin(__builtin_amdgcn_exp2f)
    return __builtin_amdgcn_exp2f(x);
#else
    return exp2f(x);
#endif
}
__device__ __forceinline__ float fast_rcp(float x) {
#if __has_builtin(__builtin_amdgcn_rcpf)
    return __builtin_amdgcn_rcpf(x);
#else
    return 1.0f / x;
#endif
}
__device__ __forceinline__ float fast_tanh(float y) {
    float t = fast_exp2(y * 2.885390081777927f);
    return (t - 1.0f) * fast_rcp(t + 1.0f);
}
__device__ __forceinline__ float fast_sigmoid(float z) {
    float t = fast_exp2(-1.4426950408889634f * z);
    return fast_rcp(1.0f + t);
}

// ---------------------------------------------------------------------------
// Pack 5 weight matrices (fp32 row-major [N][K]) into bf16 MFMA-B-fragment
// order (canonical 16x32 tile: lane = ((k>>3)&3)*16 + (n&15), j = k&7).
// ws layout: Wb(98304) | W1(65536) | W2 | Wa | Wt   (bf16 elems)
// ---------------------------------------------------------------------------
__global__ void prep_pack(const float* __restrict__ Wb, const float* __restrict__ W1,
                          const float* __restrict__ W2, const float* __restrict__ Wa,
                          const float* __restrict__ Wt, unsigned short* __restrict__ ws)
{
    int e = blockIdx.x * 256 + threadIdx.x;
    if (e >= 360448) return;
    const float* src; int K; int base;
    if (e < 98304)       { src = Wb; K = 384; base = 0; }
    else if (e < 163840) { src = W1; K = 256; base = 98304; }
    else if (e < 229376) { src = W2; K = 256; base = 163840; }
    else if (e < 294912) { src = Wa; K = 256; base = 229376; }
    else                 { src = Wt; K = 256; base = 294912; }
    int le   = e - base;
    int j    = le & 7;
    int lane = (le >> 3) & 63;
    int tile = le >> 9;
    int kt   = K >> 5;
    int ks   = tile % kt;
    int nt   = tile / kt;
    int n = nt * 16 + (lane & 15);
    int k = ks * 32 + (lane >> 4) * 8 + j;
    ws[e] = f2bf(src[n * K + k]);
}

// ---------------------------------------------------------------------------
// Fused CfC cell, BM=64 rows/block, 4 waves each owning 64 output cols.
// Weights stream via global_load_lds into a 2x16KB double buffer. The wbuf
// slices are WAVE-PRIVATE (each wave stages & reads only its own 4KB), so the
// k-step handoff needs NO barrier -- only a per-wave counted s_waitcnt
// vmcnt(4) (T4): stage(s+1) stays in flight under step s's MFMAs; in-order
// vmcnt decrement guarantees stage(s) has landed. Barriers remain only at
// input-chunk / X phase boundaries (shared LDS).
// Flat 44 steps: 0..11 = phase 1 (c,ksl), 12..43 = phase 2 (g,ks).
// LDS 64KB: X/input [0,32KB) + wbuf0 [32,48KB) + wbuf1 [48,64KB).
// 2 blocks/CU; __launch_bounds__(256,2) = 256-reg budget.
// ---------------------------------------------------------------------------
__global__ __launch_bounds__(256, 2) void cfc_fused(
    const float* __restrict__ xin, const float* __restrict__ hx,
    const float* __restrict__ ts,
    const float* __restrict__ bb, const float* __restrict__ b1,
    const float* __restrict__ b2, const float* __restrict__ ba,
    const float* __restrict__ bt,
    const unsigned short* __restrict__ wpk,
    float* __restrict__ out)
{
    __shared__ unsigned short lds[32768];   // 64 KB
    const int tid  = threadIdx.x;
    const int lane = tid & 63;
    const int w    = tid >> 6;        // wave id = output-col group (64 cols)
    const int row0 = blockIdx.x * BM;

    // stage weight tile for flat step s into wbuf pp (4KB per wave, uniform dest)
    auto STAGE = [&](int s, int pp) {
        unsigned short* wb = &lds[16384 + pp * 8192 + w * 2048];
        #pragma unroll
        for (int i = 0; i < 4; ++i) {
            size_t goff;
            if (s < 12) {                       // phase 1: Wb, i = nt
                goff = (size_t)((w * 4 + i) * 12 + s) * 512;
            } else {                            // phase 2: W1/W2/Wa/Wt, i = mat
                int s2 = s - 12, g = s2 >> 3, ks = s2 & 7;
                goff = 98304u + (size_t)i * 65536
                     + (size_t)((w * 4 + g) * 8 + ks) * 512;
            }
            gload_lds16(wpk + goff + (size_t)lane * 8, wb + i * 512);
        }
    };

    int p = 0;
    STAGE(0, 0);                        // prologue: first weight tile in flight

    // ---------------- phase 1: backbone GEMM, acc[nt][mt] -------------------
    v4f acc[4][4];
    #pragma unroll
    for (int nt = 0; nt < 4; ++nt) {
        float bv = bb[w * 64 + nt * 16 + (lane & 15)];
        v4f bvv = {bv, bv, bv, bv};
        #pragma unroll
        for (int mt = 0; mt < 4; ++mt) acc[nt][mt] = bvv;
    }

    #pragma unroll 1
    for (int c = 0; c < 3; ++c) {   // K chunks: in[0:128], hx[0:128], hx[128:256]
        const float* src = (c == 0) ? (xin + (size_t)row0 * 128)
                                    : (hx + (size_t)row0 * 256 + (c == 2 ? 128 : 0));
        const int srcld = (c == 0) ? 128 : 256;
        // issue input loads (overlap the barrier wait)
        v4f stg[8];
        #pragma unroll
        for (int it = 0; it < 8; ++it) {
            int i  = tid + it * 256;
            int r  = i >> 5;
            int c4 = i & 31;
            stg[it] = *(reinterpret_cast<const v4f*>(src + (size_t)r * srcld) + c4);
        }
        __syncthreads();            // previous chunk fully consumed by ALL waves
        #pragma unroll
        for (int it = 0; it < 8; ++it) {
            int i  = tid + it * 256;
            int r  = i >> 5;
            int c4 = i & 31;
            uint2 pk;
            pk.x = cvt_pk_bf16(stg[it][0], stg[it][1]);
            pk.y = cvt_pk_bf16(stg[it][2], stg[it][3]);
            int idx = (((r >> 4) * 4 + (c4 >> 3)) * 64 + ((c4 >> 1) & 3) * 16 + (r & 15)) * 8
                      + (c4 & 1) * 4;
            *reinterpret_cast<uint2*>(&lds[idx]) = pk;
        }
        __syncthreads();            // chunk visible to all waves

        #pragma unroll 1
        for (int ksl = 0; ksl < 4; ++ksl) {
            const int s = c * 4 + ksl;
            STAGE(s + 1, p ^ 1);    // next tile's loads fly under this compute
            // per-wave wait: stage(s) landed (<=4 outstanding = stage(s+1))
            asm volatile("s_waitcnt vmcnt(4)" ::: "memory");
            v8s a[4];
            #pragma unroll
            for (int mt = 0; mt < 4; ++mt)
                a[mt] = *reinterpret_cast<const v8s*>(&lds[((mt*4 + ksl)*64 + lane)*8]);
            const unsigned short* wb = &lds[16384 + p * 8192 + w * 2048];
            v8s bf[4];
            #pragma unroll
            for (int nt = 0; nt < 4; ++nt)
                bf[nt] = *reinterpret_cast<const v8s*>(wb + nt * 512 + lane * 8);
            #pragma unroll
            for (int nt = 0; nt < 4; ++nt)
                #pragma unroll
                for (int mt = 0; mt < 4; ++mt)
                    acc[nt][mt] = __builtin_amdgcn_mfma_f32_16x16x32_bf16(a[mt], bf[nt], acc[nt][mt], 0, 0, 0);
            p ^= 1;                 // no barrier: wbuf slices are wave-private
        }
    }

    // hoist ts (static indices only; consumed in unrolled epilogue loops)
    float tsh[4][4];
    #pragma unroll
    for (int mt = 0; mt < 4; ++mt)
        #pragma unroll
        for (int r = 0; r < 4; ++r)
            tsh[mt][r] = ts[row0 + mt*16 + ((lane >> 4) << 2) + r];

    __syncthreads();                // all waves done reading last input chunk

    // ------------- activation + write X to LDS in packed A-frag layout ------
    // D elem: row = mt*16+(lane>>4)*4+r, k2 = w*64+nt*16+(lane&15)
    #pragma unroll
    for (int nt = 0; nt < 4; ++nt)
        #pragma unroll
        for (int mt = 0; mt < 4; ++mt)
            #pragma unroll
            for (int r = 0; r < 4; ++r) {
                float xv = 1.7159f * fast_tanh(0.666f * acc[nt][mt][r]);
                int idx = ((mt*8 + w*2 + (nt >> 1)) * 64
                           + ((nt & 1)*2 + ((lane >> 3) & 1)) * 16 + (lane >> 4)*4 + r) * 8
                          + (lane & 7);
                lds[idx] = f2bf(xv);
            }
    __syncthreads();                // X visible to all waves

    // ---------------- phase 2: 4 GEMMs over X + fused epilogue --------------
    #pragma unroll 1
    for (int g = 0; g < 4; ++g) {              // n-tiles (16 cols each)
        const int n = w * 64 + g * 16 + (lane & 15);
        v4f a2[4][4];                          // [mat][mt]
        {
            float v1 = b1[n], v2 = b2[n], va = ba[n], vt = bt[n];
            v4f q1 = {v1,v1,v1,v1}, q2 = {v2,v2,v2,v2}, qa = {va,va,va,va}, qt = {vt,vt,vt,vt};
            #pragma unroll
            for (int mt = 0; mt < 4; ++mt) {
                a2[0][mt] = q1; a2[1][mt] = q2; a2[2][mt] = qa; a2[3][mt] = qt;
            }
        }
        #pragma unroll 1
        for (int ks = 0; ks < 8; ++ks) {
            const int s = 12 + g * 8 + ks;
            if (s < 43) {
                STAGE(s + 1, p ^ 1);           // wave-uniform condition
                asm volatile("s_waitcnt vmcnt(4)" ::: "memory");
            } else {
                asm volatile("s_waitcnt vmcnt(0)" ::: "memory");
            }
            v8s a[4];
            #pragma unroll
            for (int mt = 0; mt < 4; ++mt)
                a[mt] = *reinterpret_cast<const v8s*>(&lds[((mt*8 + ks)*64 + lane)*8]);
            const unsigned short* wb = &lds[16384 + p * 8192 + w * 2048];
            v8s bf[4];
            #pragma unroll
            for (int mat = 0; mat < 4; ++mat)
                bf[mat] = *reinterpret_cast<const v8s*>(wb + mat * 512 + lane * 8);
            #pragma unroll
            for (int mat = 0; mat < 4; ++mat)
                #pragma unroll
                for (int mt = 0; mt < 4; ++mt)
                    a2[mat][mt] = __builtin_amdgcn_mfma_f32_16x16x32_bf16(a[mt], bf[mat], a2[mat][mt], 0, 0, 0);
            p ^= 1;                 // no barrier: wbuf slices are wave-private
        }
        // fused epilogue: ff1, ff2, t_interp, blend, store
        // (stores/loads here only inflate vmcnt conservatively -- safe)
        #pragma unroll
        for (int mt = 0; mt < 4; ++mt) {
            int rowb = row0 + mt*16 + ((lane >> 4) << 2);
            #pragma unroll
            for (int r = 0; r < 4; ++r) {
                float ff1 = fast_tanh(a2[0][mt][r]);
                float ff2 = fast_tanh(a2[1][mt][r]);
                float ti  = fast_sigmoid(a2[2][mt][r] * tsh[mt][r] + a2[3][mt][r]);
                out[(size_t)(rowb + r) * 256 + n] = ff1 + ti * (ff2 - ff1);
            }
        }
    }
}

extern "C" void kernel_launch(void* const* d_in, const int* in_sizes, int n_in,
                              void* d_out, int out_size, void* d_ws, size_t ws_size,
                              hipStream_t stream)
{
    const float* xin = (const float*)d_in[0];
    const float* hx  = (const float*)d_in[1];
    const float* ts  = (const float*)d_in[2];
    const float* Wb  = (const float*)d_in[3];
    const float* bb  = (const float*)d_in[4];
    const float* W1  = (const float*)d_in[5];
    const float* b1  = (const float*)d_in[6];
    const float* W2  = (const float*)d_in[7];
    const float* b2  = (const float*)d_in[8];
    const float* Wa  = (const float*)d_in[9];
    const float* ba  = (const float*)d_in[10];
    const float* Wt  = (const float*)d_in[11];
    const float* bt  = (const float*)d_in[12];

    if (ws_size < 360448 * sizeof(unsigned short)) return;
    unsigned short* wpk = (unsigned short*)d_ws;

    prep_pack<<<1408, 256, 0, stream>>>(Wb, W1, W2, Wa, Wt, wpk);
    cfc_fused<<<1024, 256, 0, stream>>>(xin, hx, ts, bb, b1, b2, ba, bt, wpk,
                                        (float*)d_out);
}

// Round 9
// 79.090 us; speedup vs baseline: 2.3057x; 1.0104x over previous
//
#include <hip/hip_runtime.h>

typedef float v4f __attribute__((ext_vector_type(4)));
typedef short v8s __attribute__((ext_vector_type(8)));

#define BM 64

__device__ __forceinline__ unsigned short f2bf(float f) {
    union { float f; unsigned u; } v; v.f = f;
    unsigned u = v.u;
    u += 0x7FFFu + ((u >> 16) & 1u);   // round-to-nearest-even
    return (unsigned short)(u >> 16);
}

// pack two f32 -> two bf16 (RNE) in one instruction
__device__ __forceinline__ unsigned cvt_pk_bf16(float lo, float hi) {
    unsigned r;
    asm("v_cvt_pk_bf16_f32 %0, %1, %2" : "=v"(r) : "v"(lo), "v"(hi));
    return r;
}

// async global->LDS, 16B per lane; LDS dest is WAVE-UNIFORM base + lane*16
__device__ __forceinline__ void gload_lds16(const unsigned short* g, unsigned short* l) {
    __builtin_amdgcn_global_load_lds(
        (const __attribute__((address_space(1))) void*)(const void*)g,
        (__attribute__((address_space(3))) void*)(void*)l,
        16, 0, 0);
}

// shared-LDS sync WITHOUT draining vmcnt: ds ops are lgkm-tracked, so
// lgkmcnt(0)+s_barrier makes ds_writes visible while global_load_lds
// prefetches stay in flight across the barrier.
#define LDS_BARRIER() do {                                        \
    asm volatile("s_waitcnt lgkmcnt(0)" ::: "memory");            \
    __builtin_amdgcn_s_barrier();                                 \
    __builtin_amdgcn_sched_barrier(0);                            \
} while (0)

__device__ __forceinline__ float fast_exp2(float x) {
#if __has_builtin(__builtin_amdgcn_exp2f)
    return __builtin_amdgcn_exp2f(x);
#else
    return exp2f(x);
#endif
}
__device__ __forceinline__ float fast_rcp(float x) {
#if __has_builtin(__builtin_amdgcn_rcpf)
    return __builtin_amdgcn_rcpf(x);
#else
    return 1.0f / x;
#endif
}
__device__ __forceinline__ float fast_tanh(float y) {
    float t = fast_exp2(y * 2.885390081777927f);
    return (t - 1.0f) * fast_rcp(t + 1.0f);
}
__device__ __forceinline__ float fast_sigmoid(float z) {
    float t = fast_exp2(-1.4426950408889634f * z);
    return fast_rcp(1.0f + t);
}

// ---------------------------------------------------------------------------
// Pack 5 weight matrices (fp32 row-major [N][K]) into bf16 MFMA-B-fragment
// order (canonical 16x32 tile: lane = ((k>>3)&3)*16 + (n&15), j = k&7).
// ws layout: Wb(98304) | W1(65536) | W2 | Wa | Wt   (bf16 elems)
// ---------------------------------------------------------------------------
__global__ void prep_pack(const float* __restrict__ Wb, const float* __restrict__ W1,
                          const float* __restrict__ W2, const float* __restrict__ Wa,
                          const float* __restrict__ Wt, unsigned short* __restrict__ ws)
{
    int e = blockIdx.x * 256 + threadIdx.x;
    if (e >= 360448) return;
    const float* src; int K; int base;
    if (e < 98304)       { src = Wb; K = 384; base = 0; }
    else if (e < 163840) { src = W1; K = 256; base = 98304; }
    else if (e < 229376) { src = W2; K = 256; base = 163840; }
    else if (e < 294912) { src = Wa; K = 256; base = 229376; }
    else                 { src = Wt; K = 256; base = 294912; }
    int le   = e - base;
    int j    = le & 7;
    int lane = (le >> 3) & 63;
    int tile = le >> 9;
    int kt   = K >> 5;
    int ks   = tile % kt;
    int nt   = tile / kt;
    int n = nt * 16 + (lane & 15);
    int k = ks * 32 + (lane >> 4) * 8 + j;
    ws[e] = f2bf(src[n * K + k]);
}

// ---------------------------------------------------------------------------
// Fused CfC cell, BM=64 rows/block, 4 waves each owning 64 output cols.
// Weight stream: global_load_lds into 3 wave-private 16KB buffers,
// issue-ahead-2 (STAGE(s+2) at step s), per-wave s_waitcnt vmcnt(8) -- the
// confirmed stage was issued ~2 steps (~300cyc) ago, so the wait is ~free.
// Raw lgkmcnt+s_barrier at shared-LDS sync points keeps the weight pipeline
// in flight across chunk/phase boundaries (no vmcnt(0) drain anywhere).
// Flat 44 steps: 0..11 = phase 1 (c,ksl), 12..43 = phase 2 (g,ks).
// LDS 80KB: X/input [0,32KB) + wbuf[3] at 32/48/64KB. 2 blocks/CU.
// ---------------------------------------------------------------------------
__global__ __launch_bounds__(256, 2) void cfc_fused(
    const float* __restrict__ xin, const float* __restrict__ hx,
    const float* __restrict__ ts,
    const float* __restrict__ bb, const float* __restrict__ b1,
    const float* __restrict__ b2, const float* __restrict__ ba,
    const float* __restrict__ bt,
    const unsigned short* __restrict__ wpk,
    float* __restrict__ out)
{
    __shared__ unsigned short lds[40960];   // 80 KB
    const int tid  = threadIdx.x;
    const int lane = tid & 63;
    const int w    = tid >> 6;        // wave id = output-col group (64 cols)
    const int row0 = blockIdx.x * BM;

    // stage weight tile for flat step s into wbuf[s%3] (4KB per wave)
    auto STAGE = [&](int s) {
        unsigned short* wb = &lds[16384 + (s % 3) * 8192 + w * 2048];
        #pragma unroll
        for (int i = 0; i < 4; ++i) {
            size_t goff;
            if (s < 12) {                       // phase 1: Wb, i = nt
                goff = (size_t)((w * 4 + i) * 12 + s) * 512;
            } else {                            // phase 2: W1/W2/Wa/Wt, i = mat
                int s2 = s - 12, g = s2 >> 3, ks = s2 & 7;
                goff = 98304u + (size_t)i * 65536
                     + (size_t)((w * 4 + g) * 8 + ks) * 512;
            }
            gload_lds16(wpk + goff + (size_t)lane * 8, wb + i * 512);
        }
    };

    STAGE(0); STAGE(1);                 // prologue: two tiles in flight

    // ---------------- phase 1: backbone GEMM, acc[nt][mt] -------------------
    v4f acc[4][4];
    #pragma unroll
    for (int nt = 0; nt < 4; ++nt) {
        float bv = bb[w * 64 + nt * 16 + (lane & 15)];
        v4f bvv = {bv, bv, bv, bv};
        #pragma unroll
        for (int mt = 0; mt < 4; ++mt) acc[nt][mt] = bvv;
    }

    #pragma unroll 1
    for (int c = 0; c < 3; ++c) {   // K chunks: in[0:128], hx[0:128], hx[128:256]
        const float* src = (c == 0) ? (xin + (size_t)row0 * 128)
                                    : (hx + (size_t)row0 * 256 + (c == 2 ? 128 : 0));
        const int srcld = (c == 0) ? 128 : 256;
        // issue input loads (overlap the barrier wait)
        v4f stg[8];
        #pragma unroll
        for (int it = 0; it < 8; ++it) {
            int i  = tid + it * 256;
            int r  = i >> 5;
            int c4 = i & 31;
            stg[it] = *(reinterpret_cast<const v4f*>(src + (size_t)r * srcld) + c4);
        }
        LDS_BARRIER();              // previous chunk fully consumed by ALL waves
        #pragma unroll
        for (int it = 0; it < 8; ++it) {
            int i  = tid + it * 256;
            int r  = i >> 5;
            int c4 = i & 31;
            uint2 pk;
            pk.x = cvt_pk_bf16(stg[it][0], stg[it][1]);
            pk.y = cvt_pk_bf16(stg[it][2], stg[it][3]);
            int idx = (((r >> 4) * 4 + (c4 >> 3)) * 64 + ((c4 >> 1) & 3) * 16 + (r & 15)) * 8
                      + (c4 & 1) * 4;
            *reinterpret_cast<uint2*>(&lds[idx]) = pk;
        }
        LDS_BARRIER();              // chunk visible to all waves

        #pragma unroll 1
        for (int ksl = 0; ksl < 4; ++ksl) {
            const int s = c * 4 + ksl;
            STAGE(s + 2);           // ahead-2: lands during the next 2 steps
            // confirm stage(s): leaves s+1, s+2 (8 loads) outstanding
            asm volatile("s_waitcnt vmcnt(8)" ::: "memory");
            v8s a[4];
            #pragma unroll
            for (int mt = 0; mt < 4; ++mt)
                a[mt] = *reinterpret_cast<const v8s*>(&lds[((mt*4 + ksl)*64 + lane)*8]);
            const unsigned short* wb = &lds[16384 + (s % 3) * 8192 + w * 2048];
            v8s bf[4];
            #pragma unroll
            for (int nt = 0; nt < 4; ++nt)
                bf[nt] = *reinterpret_cast<const v8s*>(wb + nt * 512 + lane * 8);
            #pragma unroll
            for (int nt = 0; nt < 4; ++nt)
                #pragma unroll
                for (int mt = 0; mt < 4; ++mt)
                    acc[nt][mt] = __builtin_amdgcn_mfma_f32_16x16x32_bf16(a[mt], bf[nt], acc[nt][mt], 0, 0, 0);
            // no barrier: wbuf slices are wave-private
        }
    }

    // hoist ts (static indices only; consumed in unrolled epilogue loops)
    float tsh[4][4];
    #pragma unroll
    for (int mt = 0; mt < 4; ++mt)
        #pragma unroll
        for (int r = 0; r < 4; ++r)
            tsh[mt][r] = ts[row0 + mt*16 + ((lane >> 4) << 2) + r];

    LDS_BARRIER();                  // all waves done reading last input chunk

    // ------------- activation + write X to LDS in packed A-frag layout ------
    // D elem: row = mt*16+(lane>>4)*4+r, k2 = w*64+nt*16+(lane&15)
    #pragma unroll
    for (int nt = 0; nt < 4; ++nt)
        #pragma unroll
        for (int mt = 0; mt < 4; ++mt)
            #pragma unroll
            for (int r = 0; r < 4; ++r) {
                float xv = 1.7159f * fast_tanh(0.666f * acc[nt][mt][r]);
                int idx = ((mt*8 + w*2 + (nt >> 1)) * 64
                           + ((nt & 1)*2 + ((lane >> 3) & 1)) * 16 + (lane >> 4)*4 + r) * 8
                          + (lane & 7);
                lds[idx] = f2bf(xv);
            }
    LDS_BARRIER();                  // X visible to all waves

    // ---------------- phase 2: 4 GEMMs over X + fused epilogue --------------
    #pragma unroll 1
    for (int g = 0; g < 4; ++g) {              // n-tiles (16 cols each)
        const int n = w * 64 + g * 16 + (lane & 15);
        v4f a2[4][4];                          // [mat][mt]
        {
            float v1 = b1[n], v2 = b2[n], va = ba[n], vt = bt[n];
            v4f q1 = {v1,v1,v1,v1}, q2 = {v2,v2,v2,v2}, qa = {va,va,va,va}, qt = {vt,vt,vt,vt};
            #pragma unroll
            for (int mt = 0; mt < 4; ++mt) {
                a2[0][mt] = q1; a2[1][mt] = q2; a2[2][mt] = qa; a2[3][mt] = qt;
            }
        }
        #pragma unroll 1
        for (int ks = 0; ks < 8; ++ks) {
            const int s = 12 + g * 8 + ks;
            if (s <= 41) {                     // wave-uniform branches
                STAGE(s + 2);
                asm volatile("s_waitcnt vmcnt(8)" ::: "memory");
            } else if (s == 42) {
                asm volatile("s_waitcnt vmcnt(4)" ::: "memory");
            } else {
                asm volatile("s_waitcnt vmcnt(0)" ::: "memory");
            }
            v8s a[4];
            #pragma unroll
            for (int mt = 0; mt < 4; ++mt)
                a[mt] = *reinterpret_cast<const v8s*>(&lds[((mt*8 + ks)*64 + lane)*8]);
            const unsigned short* wb = &lds[16384 + (s % 3) * 8192 + w * 2048];
            v8s bf[4];
            #pragma unroll
            for (int mat = 0; mat < 4; ++mat)
                bf[mat] = *reinterpret_cast<const v8s*>(wb + mat * 512 + lane * 8);
            #pragma unroll
            for (int mat = 0; mat < 4; ++mat)
                #pragma unroll
                for (int mt = 0; mt < 4; ++mt)
                    a2[mat][mt] = __builtin_amdgcn_mfma_f32_16x16x32_bf16(a[mt], bf[mat], a2[mat][mt], 0, 0, 0);
            // no barrier: wbuf slices are wave-private
        }
        // fused epilogue: ff1, ff2, t_interp, blend, store.  Stores sit older
        // than later stages in the vmcnt queue -> later waits are conservative
        // (may briefly drain stores once per g), never unsafe.
        #pragma unroll
        for (int mt = 0; mt < 4; ++mt) {
            int rowb = row0 + mt*16 + ((lane >> 4) << 2);
            #pragma unroll
            for (int r = 0; r < 4; ++r) {
                float ff1 = fast_tanh(a2[0][mt][r]);
                float ff2 = fast_tanh(a2[1][mt][r]);
                float ti  = fast_sigmoid(a2[2][mt][r] * tsh[mt][r] + a2[3][mt][r]);
                out[(size_t)(rowb + r) * 256 + n] = ff1 + ti * (ff2 - ff1);
            }
        }
    }
}

extern "C" void kernel_launch(void* const* d_in, const int* in_sizes, int n_in,
                              void* d_out, int out_size, void* d_ws, size_t ws_size,
                              hipStream_t stream)
{
    const float* xin = (const float*)d_in[0];
    const float* hx  = (const float*)d_in[1];
    const float* ts  = (const float*)d_in[2];
    const float* Wb  = (const float*)d_in[3];
    const float* bb  = (const float*)d_in[4];
    const float* W1  = (const float*)d_in[5];
    const float* b1  = (const float*)d_in[6];
    const float* W2  = (const float*)d_in[7];
    const float* b2  = (const float*)d_in[8];
    const float* Wa  = (const float*)d_in[9];
    const float* ba  = (const float*)d_in[10];
    const float* Wt  = (const float*)d_in[11];
    const float* bt  = (const float*)d_in[12];

    if (ws_size < 360448 * sizeof(unsigned short)) return;
    unsigned short* wpk = (unsigned short*)d_ws;

    prep_pack<<<1408, 256, 0, stream>>>(Wb, W1, W2, Wa, Wt, wpk);
    cfc_fused<<<1024, 256, 0, stream>>>(xin, hx, ts, bb, b1, b2, ba, bt, wpk,
                                        (float*)d_out);
}